// Round 7
// baseline (64.915 us; speedup 1.0000x reference)
//
#include <hip/hip_runtime.h>
#include <math.h>

#define NB 128
#define NC 8
#define NV 16384
#define NK 64
#define NR 128

// flat output offsets (elements, f32)
#define OFF_MASKS  0
#define OFF_VP     2097152
#define OFF_THETAS 8388608
#define OFF_ALPHAS 8388736
#define OFF_ROT    8388864
#define OFF_SCALES 8389376
#define OFF_DEPTHS 8389504
#define OFF_C2D    8389632
#define OFF_TRANS  8389888
#define OFF_CLP    8390272

#define PI_F     3.14159265358979323846f
#define TWOPI_F  6.28318530717958647692f

// d_ws layout:
//   Wi[0..8]        scnt: class prefix over records
//   Wi[16..24]      cts:  class prefix over col-tiles (ceil(n_c/5) each)
//   Wi[32+r]        record -> batch id (class-sorted, r = 0..127)
//   Wf[256+r*8]     params per record: scale,qw,qy,tx,ty,tz,feff,pad
//   Wf[1280...]     Bpack (ushort): per (coltile t, kstep ks): 512 bf16
//                   elem (t*2+ks)*512 + lane*8 + j <-> B[col=lane&15][k=ks*32+(lane>>4)*8+j]

typedef short  short8 __attribute__((ext_vector_type(8)));
typedef float  f32x4  __attribute__((ext_vector_type(4)));

__device__ __forceinline__ unsigned short f2bf(float f) {
  unsigned int u = __float_as_uint(f);
  unsigned int r = (u + 0x7FFFu + ((u >> 16) & 1u)) >> 16;   // RNE
  return (unsigned short)r;
}

// ---- kernel 1: scalars + tables + bf16 B-pack (17 blocks) -------------------
__global__ __launch_bounds__(256) void prep_kernel(
    const float* __restrict__ roi, const float* __restrict__ focals,
    const float* __restrict__ td,  const float* __restrict__ t2,
    const float* __restrict__ ls,  const float* __restrict__ ld,
    const float* __restrict__ cp,  const float* __restrict__ fc,
    float* __restrict__ out, int* __restrict__ Wi, float* __restrict__ Wf) {
  int tid = threadIdx.x;
  int bx  = blockIdx.x;

  __shared__ int cls_sh[NB];
  __shared__ int rb_sh[NB];
  __shared__ int scnt_sh[NC + 1];
  __shared__ int cts_sh[NC + 1];

  int b = tid;
  int cls = 0;
  if (b < NB) {
    float pmax = cp[b * NC];
    for (int c = 1; c < NC; ++c) {
      float pv = cp[b * NC + c];
      if (pv > pmax) { pmax = pv; cls = c; }
    }
    cls_sh[b] = cls;
  }
  __syncthreads();
  if (tid <= NC) {
    int cnt = 0;
    for (int j = 0; j < NB; ++j) cnt += (cls_sh[j] < tid);
    scnt_sh[tid] = cnt;
  }
  __syncthreads();
  if (tid == 0) {
    cts_sh[0] = 0;
    for (int c = 0; c < NC; ++c) {
      int n = scnt_sh[c + 1] - scnt_sh[c];
      cts_sh[c + 1] = cts_sh[c] + (n + 4) / 5;
    }
  }
  int rank = 0;
  if (b < NB) {
    rank = scnt_sh[cls];
    for (int j = 0; j < b; ++j) rank += (cls_sh[j] == cls);
    rb_sh[rank] = b;
  }
  __syncthreads();

  if (bx == 0) {
    if (b < NB) {
      float r0 = roi[b * 4 + 0], r1 = roi[b * 4 + 1];
      float r2 = roi[b * 4 + 2], r3 = roi[b * 4 + 3];
      float dx = r2 - r0, dy = r3 - r1;
      float mx = 0.5f * (r2 + r0), my = 0.5f * (r3 + r1);
      float theta = atan2f(td[b * 2 + 1], td[b * 2 + 0]);
      float qw = cosf(0.5f * theta);
      float qy = sinf(0.5f * theta);
      float area  = dx * dy;
      float scale = expf(ls[b]);
      float depth = sqrtf(expf(ld[b]) / area);
      float cx = mx + t2[b * 2 + 0] * dx;
      float cy = my + t2[b * 2 + 1] * dy;
      float tux = cy, tuy = -cx;
      float n = sqrtf(tux * tux + tuy * tuy + 1.0f);
      float tx_ = depth * (tux / n);
      float ty_ = depth * (tuy / n);
      float tz_ = depth * (-1.0f / n);
      float alpha = -(theta - atanf(tx_ / tz_));
      float a  = alpha + PI_F;
      float rr = fmodf(a, TWOPI_F);
      if (rr < 0.0f) rr += TWOPI_F;
      float alpha_out = rr - PI_F;
      float pmax = cp[b * NC];
      for (int c = 1; c < NC; ++c) pmax = fmaxf(pmax, cp[b * NC + c]);
      float feff = 2.0f * focals[b] / (float)NR;

      out[OFF_THETAS + b]      = theta;
      out[OFF_ALPHAS + b]      = alpha_out;
      out[OFF_ROT + 4 * b + 0] = qw;
      out[OFF_ROT + 4 * b + 1] = 0.0f;
      out[OFF_ROT + 4 * b + 2] = qy;
      out[OFF_ROT + 4 * b + 3] = 0.0f;
      out[OFF_SCALES + b]      = scale;
      out[OFF_DEPTHS + b]      = depth;
      out[OFF_C2D + 2 * b + 0] = cx;
      out[OFF_C2D + 2 * b + 1] = cy;
      out[OFF_TRANS + 3 * b + 0] = tx_;
      out[OFF_TRANS + 3 * b + 1] = ty_;
      out[OFF_TRANS + 3 * b + 2] = tz_;
      out[OFF_CLP + b]         = logf(pmax);

      float* par = Wf + 256 + rank * 8;
      par[0] = scale; par[1] = qw; par[2] = qy; par[3] = tx_;
      par[4] = ty_;   par[5] = tz_; par[6] = feff; par[7] = 0.0f;
      Wi[32 + rank] = b;
    }
    if (tid <= NC) {
      Wi[tid]      = scnt_sh[tid];
      Wi[16 + tid] = cts_sh[tid];
    }
  } else {
    // blocks 1..16: pack coeffs into bf16 B-fragments
    unsigned short* BPu = (unsigned short*)(Wf + 1280);
    int total = cts_sh[NC] * 1024;      // elements
    for (int g = (bx - 1) * 256 + tid; g < total; g += 16 * 256) {
      int t   = g >> 10;
      int r10 = g & 1023;
      int ks  = r10 >> 9;
      int li  = (r10 >> 3) & 63;
      int j   = r10 & 7;
      int col = li & 15, kg = li >> 4;
      int k   = ks * 32 + kg * 8 + j;
      int c = 0;
      while (!(t >= cts_sh[c] && t < cts_sh[c + 1])) ++c;
      int local_ct = t - cts_sh[c];
      int n_c = scnt_sh[c + 1] - scnt_sh[c];
      float val = 0.0f;
      if (col < 15) {
        int lr = col / 3, comp = col - 3 * lr;
        int lrec = local_ct * 5 + lr;
        if (lrec < n_c) {
          int bb = rb_sh[scnt_sh[c] + lrec];
          val = fc[((size_t)(bb * NC + c) * NK + k) * 3 + comp];
        }
      }
      BPu[(size_t)g] = f2bf(val);
    }
  }
}

// ---- kernel 2: per-class GEMM + transform, coalesced vp store (no mask) -----
// grid (256, 8): x = 64-vertex super-tile, y = class. 4 waves/block.
__global__ __launch_bounds__(256) void verts_kernel(
    const float* __restrict__ basev,    // (C, V, 3)
    const float* __restrict__ basis,    // (C, V, K)
    const int*   __restrict__ Wi,
    const float* __restrict__ Wf,
    float* __restrict__ out) {
  int c   = blockIdx.y;
  int ct0 = Wi[16 + c], ct1 = Wi[16 + c + 1];
  if (ct0 >= ct1) return;
  int rec0  = Wi[c];
  int nrecs = Wi[c + 1] - rec0;

  __shared__ unsigned short s_B[8 * 1024];   // up to 8 staged col-tiles (16 KB)
  __shared__ float s_vp[4][256];             // per-wave store staging (4 KB)

  int ntile = ct1 - ct0;
  if (ntile > 8) ntile = 8;
  {
    const uint4* Bg = (const uint4*)((const unsigned short*)(Wf + 1280) +
                                     (size_t)ct0 * 1024);
    uint4* Bs = (uint4*)s_B;
    for (int i = threadIdx.x; i < ntile * 128; i += 256) Bs[i] = Bg[i];
  }

  int wave = threadIdx.x >> 6;
  int lane = threadIdx.x & 63;
  int v0   = blockIdx.x * 64 + wave * 16;
  int row  = lane & 15, kg = lane >> 4;

  // A fragments: basis[c][v0+row][k], k = ks*32 + kg*8 + j   (f32 -> bf16)
  const float* ab = basis + ((size_t)c * NV + (v0 + row)) * NK + kg * 8;
  float4 a0 = *(const float4*)(ab);
  float4 a1 = *(const float4*)(ab + 4);
  float4 a2 = *(const float4*)(ab + 32);
  float4 a3 = *(const float4*)(ab + 36);
  short8 A0, A1;
  A0[0]=f2bf(a0.x); A0[1]=f2bf(a0.y); A0[2]=f2bf(a0.z); A0[3]=f2bf(a0.w);
  A0[4]=f2bf(a1.x); A0[5]=f2bf(a1.y); A0[6]=f2bf(a1.z); A0[7]=f2bf(a1.w);
  A1[0]=f2bf(a2.x); A1[1]=f2bf(a2.y); A1[2]=f2bf(a2.z); A1[3]=f2bf(a2.w);
  A1[4]=f2bf(a3.x); A1[5]=f2bf(a3.y); A1[6]=f2bf(a3.z); A1[7]=f2bf(a3.w);

  // epilogue lane roles: q -> (record lr, component comp); rowg -> vertex group
  int q = lane & 15, rowg = lane >> 4;
  int lr = q / 3, comp = q - 3 * lr;
  bool qok = (q < 15);
  float bvx[4], bvy[4], bvz[4];
#pragma unroll
  for (int j = 0; j < 4; ++j) {
    const float* bp = basev + ((size_t)c * NV + (v0 + rowg * 4 + j)) * 3;
    bvx[j] = bp[0]; bvy[j] = bp[1]; bvz[j] = bp[2];
  }
  int sbase = lane & 48;
  int sx = sbase | (qok ? 3 * lr     : 0);
  int sy = sbase | (qok ? 3 * lr + 1 : 0);
  int sz = sbase | (qok ? 3 * lr + 2 : 0);

  // readout lane roles
  int rrec = lane / 12;            // 0..4 (lanes >= 60 idle)
  int roff = (lane % 12) * 4;      // float4 offset within the record's 48

  __syncthreads();   // s_B staged

  for (int t = ct0; t < ct1; ++t) {
    short8 B0, B1;
    if (t - ct0 < 8) {
      B0 = *(short8*)&s_B[(size_t)(t - ct0) * 1024 + lane * 8];
      B1 = *(short8*)&s_B[(size_t)(t - ct0) * 1024 + 512 + lane * 8];
    } else {
      const float4* BP4 = (const float4*)(Wf + 1280);
      float4 rb0 = BP4[(size_t)(t * 2 + 0) * 64 + lane];
      float4 rb1 = BP4[(size_t)(t * 2 + 1) * 64 + lane];
      B0 = *(short8*)&rb0; B1 = *(short8*)&rb1;
    }
    f32x4 acc = {0.0f, 0.0f, 0.0f, 0.0f};
    acc = __builtin_amdgcn_mfma_f32_16x16x32_bf16(A0, B0, acc, 0, 0, 0);
    acc = __builtin_amdgcn_mfma_f32_16x16x32_bf16(A1, B1, acc, 0, 0, 0);

    int nrec_ct = nrecs - (t - ct0) * 5;
    nrec_ct = (nrec_ct > 5) ? 5 : nrec_ct;
    bool valid = qok && (lr < nrec_ct);
    int rec = rec0 + (t - ct0) * 5 + (valid ? lr : 0);
    float4 P0 = *(const float4*)(Wf + 256 + rec * 8);
    float4 P1 = *(const float4*)(Wf + 256 + rec * 8 + 4);
    float scale = P0.x, qw = P0.y, qy = P0.z, tx = P0.w;
    float ty = P1.x, tz = P1.y, feff = P1.z;

#pragma unroll
    for (int j = 0; j < 4; ++j) {
      float dx_ = __shfl(acc[j], sx);
      float dy_ = __shfl(acc[j], sy);
      float dz_ = __shfl(acc[j], sz);

      float vx = (bvx[j] + dx_) * scale;
      float vy = (bvy[j] + dy_) * scale;
      float vz = (bvz[j] + dz_) * scale;
      float t2x = 2.0f * qy * vz;
      float t2z = -2.0f * qy * vx;
      float rx = vx + qw * t2x + qy * t2z;
      float ry = vy;
      float rz = vz + qw * t2z - qy * t2x;
      float wx = rx + tx, wy = ry + ty, wz = rz + tz;

      float zv = wz;
      float zsafe = (zv > -1e-4f) ? -1e-4f : zv;
      float inv = feff / (-zsafe);
      float px = (wx * inv * 0.5f + 0.5f) * (float)NR;
      float py = (wy * inv * 0.5f + 0.5f) * (float)NR;

      float ov = (comp == 0) ? px : ((comp == 1) ? py : -zv);
      if (qok) s_vp[wave][lr * 48 + (rowg * 4 + j) * 3 + comp] = ov;
    }
    // in-order per-wave DS: reads below see the writes above (no barrier)
    if (lane < 60 && rrec < nrec_ct) {
      float4 val = *(float4*)&s_vp[wave][rrec * 48 + roff];
      int rrec_g = rec0 + (t - ct0) * 5 + rrec;
      int bb = Wi[32 + rrec_g];
      *(float4*)&out[OFF_VP + ((size_t)bb * NV + v0) * 3 + roff] = val;
    }
  }
}

// ---- kernel 3: batch-major mask build via LDS tile (replaces fill+scatter) --
__global__ __launch_bounds__(256) void mask_kernel(float* __restrict__ out) {
  int b = blockIdx.x;
  __shared__ float m[NR * NR];   // 64 KB
  float4 z4; z4.x = 0.0f; z4.y = 0.0f; z4.z = 0.0f; z4.w = 0.0f;
  for (int i = threadIdx.x; i < NR * NR / 4; i += 256) *(float4*)&m[i * 4] = z4;
  __syncthreads();
  const float* vb = out + OFF_VP + (size_t)b * NV * 3;
  for (int v = threadIdx.x; v < NV; v += 256) {
    float px = vb[v * 3 + 0];
    float py = vb[v * 3 + 1];
    int xi = (int)fminf(fmaxf(px, 0.0f), 127.0f);
    int yi = (int)fminf(fmaxf(py, 0.0f), 127.0f);
    m[yi * NR + xi] = 1.0f;     // same-address races all write 1.0f
  }
  __syncthreads();
  float4* mo = (float4*)(out + OFF_MASKS + ((size_t)b << 14));
  for (int i = threadIdx.x; i < NR * NR / 4; i += 256) mo[i] = *(float4*)&m[i * 4];
}

extern "C" void kernel_launch(void* const* d_in, const int* in_sizes, int n_in,
                              void* d_out, int out_size, void* d_ws, size_t ws_size,
                              hipStream_t stream) {
  const float* roi    = (const float*)d_in[0];
  const float* focals = (const float*)d_in[1];
  const float* td     = (const float*)d_in[2];
  const float* t2     = (const float*)d_in[3];
  const float* ls     = (const float*)d_in[4];
  const float* ld     = (const float*)d_in[5];
  const float* cp     = (const float*)d_in[6];
  const float* fc     = (const float*)d_in[7];
  const float* bv     = (const float*)d_in[8];
  const float* fb     = (const float*)d_in[9];
  float* out = (float*)d_out;
  int*   Wi  = (int*)d_ws;
  float* Wf  = (float*)d_ws;

  prep_kernel<<<dim3(17), dim3(256), 0, stream>>>(
      roi, focals, td, t2, ls, ld, cp, fc, out, Wi, Wf);
  // MEASUREMENT ROUND: verts launched twice (bit-identical, idempotent).
  // dur(R7) - dur(R6) == one verts instance's true in-graph cost.
  verts_kernel<<<dim3(256, 8), dim3(256), 0, stream>>>(
      bv, fb, Wi, Wf, out);
  verts_kernel<<<dim3(256, 8), dim3(256), 0, stream>>>(
      bv, fb, Wi, Wf, out);
  mask_kernel<<<dim3(NB), dim3(256), 0, stream>>>(out);
}

// Round 8
// 43.351 us; speedup vs baseline: 1.4974x; 1.4974x over previous
//
#include <hip/hip_runtime.h>
#include <math.h>

#define NB 128
#define NC 8
#define NV 16384
#define NK 64
#define NR 128

// flat output offsets (elements, f32)
#define OFF_MASKS  0
#define OFF_VP     2097152
#define OFF_THETAS 8388608
#define OFF_ALPHAS 8388736
#define OFF_ROT    8388864
#define OFF_SCALES 8389376
#define OFF_DEPTHS 8389504
#define OFF_C2D    8389632
#define OFF_TRANS  8389888
#define OFF_CLP    8390272

#define PI_F     3.14159265358979323846f
#define TWOPI_F  6.28318530717958647692f

// d_ws layout:
//   Wi[0..8]        scnt: class prefix over records
//   Wi[16..24]      cts:  class prefix over col-tiles (ceil(n_c/5) each)
//   Wi[32+r]        record -> batch id (class-sorted, r = 0..127)
//   Wf[256+r*8]     params per record: scale,qw,qy,tx,ty,tz,feff,pad
//   Wf[1280...]     Bpack (ushort): per (coltile t, kstep ks): 512 bf16
//                   elem (t*2+ks)*512 + lane*8 + j <-> B[col=lane&15][k=ks*32+(lane>>4)*8+j]

typedef short  short8 __attribute__((ext_vector_type(8)));
typedef float  f32x4  __attribute__((ext_vector_type(4)));

__device__ __forceinline__ unsigned short f2bf(float f) {
  unsigned int u = __float_as_uint(f);
  unsigned int r = (u + 0x7FFFu + ((u >> 16) & 1u)) >> 16;   // RNE
  return (unsigned short)r;
}

// ---- kernel 1: scalars + tables + bf16 B-pack (17 blocks) -------------------
__global__ __launch_bounds__(256) void prep_kernel(
    const float* __restrict__ roi, const float* __restrict__ focals,
    const float* __restrict__ td,  const float* __restrict__ t2,
    const float* __restrict__ ls,  const float* __restrict__ ld,
    const float* __restrict__ cp,  const float* __restrict__ fc,
    float* __restrict__ out, int* __restrict__ Wi, float* __restrict__ Wf) {
  int tid = threadIdx.x;
  int bx  = blockIdx.x;

  __shared__ int cls_sh[NB];
  __shared__ int rb_sh[NB];
  __shared__ int scnt_sh[NC + 1];
  __shared__ int cts_sh[NC + 1];

  int b = tid;
  int cls = 0;
  if (b < NB) {
    float pmax = cp[b * NC];
    for (int c = 1; c < NC; ++c) {
      float pv = cp[b * NC + c];
      if (pv > pmax) { pmax = pv; cls = c; }
    }
    cls_sh[b] = cls;
  }
  __syncthreads();
  if (tid <= NC) {
    int cnt = 0;
    for (int j = 0; j < NB; ++j) cnt += (cls_sh[j] < tid);
    scnt_sh[tid] = cnt;
  }
  __syncthreads();
  if (tid == 0) {
    cts_sh[0] = 0;
    for (int c = 0; c < NC; ++c) {
      int n = scnt_sh[c + 1] - scnt_sh[c];
      cts_sh[c + 1] = cts_sh[c] + (n + 4) / 5;
    }
  }
  int rank = 0;
  if (b < NB) {
    rank = scnt_sh[cls];
    for (int j = 0; j < b; ++j) rank += (cls_sh[j] == cls);
    rb_sh[rank] = b;
  }
  __syncthreads();

  if (bx == 0) {
    if (b < NB) {
      float r0 = roi[b * 4 + 0], r1 = roi[b * 4 + 1];
      float r2 = roi[b * 4 + 2], r3 = roi[b * 4 + 3];
      float dx = r2 - r0, dy = r3 - r1;
      float mx = 0.5f * (r2 + r0), my = 0.5f * (r3 + r1);
      float theta = atan2f(td[b * 2 + 1], td[b * 2 + 0]);
      float qw = cosf(0.5f * theta);
      float qy = sinf(0.5f * theta);
      float area  = dx * dy;
      float scale = expf(ls[b]);
      float depth = sqrtf(expf(ld[b]) / area);
      float cx = mx + t2[b * 2 + 0] * dx;
      float cy = my + t2[b * 2 + 1] * dy;
      float tux = cy, tuy = -cx;
      float n = sqrtf(tux * tux + tuy * tuy + 1.0f);
      float tx_ = depth * (tux / n);
      float ty_ = depth * (tuy / n);
      float tz_ = depth * (-1.0f / n);
      float alpha = -(theta - atanf(tx_ / tz_));
      float a  = alpha + PI_F;
      float rr = fmodf(a, TWOPI_F);
      if (rr < 0.0f) rr += TWOPI_F;
      float alpha_out = rr - PI_F;
      float pmax = cp[b * NC];
      for (int c = 1; c < NC; ++c) pmax = fmaxf(pmax, cp[b * NC + c]);
      float feff = 2.0f * focals[b] / (float)NR;

      out[OFF_THETAS + b]      = theta;
      out[OFF_ALPHAS + b]      = alpha_out;
      out[OFF_ROT + 4 * b + 0] = qw;
      out[OFF_ROT + 4 * b + 1] = 0.0f;
      out[OFF_ROT + 4 * b + 2] = qy;
      out[OFF_ROT + 4 * b + 3] = 0.0f;
      out[OFF_SCALES + b]      = scale;
      out[OFF_DEPTHS + b]      = depth;
      out[OFF_C2D + 2 * b + 0] = cx;
      out[OFF_C2D + 2 * b + 1] = cy;
      out[OFF_TRANS + 3 * b + 0] = tx_;
      out[OFF_TRANS + 3 * b + 1] = ty_;
      out[OFF_TRANS + 3 * b + 2] = tz_;
      out[OFF_CLP + b]         = logf(pmax);

      float* par = Wf + 256 + rank * 8;
      par[0] = scale; par[1] = qw; par[2] = qy; par[3] = tx_;
      par[4] = ty_;   par[5] = tz_; par[6] = feff; par[7] = 0.0f;
      Wi[32 + rank] = b;
    }
    if (tid <= NC) {
      Wi[tid]      = scnt_sh[tid];
      Wi[16 + tid] = cts_sh[tid];
    }
  } else {
    // blocks 1..16: pack coeffs into bf16 B-fragments
    unsigned short* BPu = (unsigned short*)(Wf + 1280);
    int total = cts_sh[NC] * 1024;      // elements
    for (int g = (bx - 1) * 256 + tid; g < total; g += 16 * 256) {
      int t   = g >> 10;
      int r10 = g & 1023;
      int ks  = r10 >> 9;
      int li  = (r10 >> 3) & 63;
      int j   = r10 & 7;
      int col = li & 15, kg = li >> 4;
      int k   = ks * 32 + kg * 8 + j;
      int c = 0;
      while (!(t >= cts_sh[c] && t < cts_sh[c + 1])) ++c;
      int local_ct = t - cts_sh[c];
      int n_c = scnt_sh[c + 1] - scnt_sh[c];
      float val = 0.0f;
      if (col < 15) {
        int lr = col / 3, comp = col - 3 * lr;
        int lrec = local_ct * 5 + lr;
        if (lrec < n_c) {
          int bb = rb_sh[scnt_sh[c] + lrec];
          val = fc[((size_t)(bb * NC + c) * NK + k) * 3 + comp];
        }
      }
      BPu[(size_t)g] = f2bf(val);
    }
  }
}

// ---- kernel 2: per-class GEMM + transform, coalesced vp store (no mask) -----
// grid (256, 8): x = 64-vertex super-tile, y = class. 4 waves/block.
__global__ __launch_bounds__(256) void verts_kernel(
    const float* __restrict__ basev,    // (C, V, 3)
    const float* __restrict__ basis,    // (C, V, K)
    const int*   __restrict__ Wi,
    const float* __restrict__ Wf,
    float* __restrict__ out) {
  int c   = blockIdx.y;
  int ct0 = Wi[16 + c], ct1 = Wi[16 + c + 1];
  if (ct0 >= ct1) return;
  int rec0  = Wi[c];
  int nrecs = Wi[c + 1] - rec0;

  __shared__ unsigned short s_B[8 * 1024];   // up to 8 staged col-tiles (16 KB)
  __shared__ float s_vp[4][256];             // per-wave store staging (4 KB)

  int ntile = ct1 - ct0;
  if (ntile > 8) ntile = 8;
  {
    const uint4* Bg = (const uint4*)((const unsigned short*)(Wf + 1280) +
                                     (size_t)ct0 * 1024);
    uint4* Bs = (uint4*)s_B;
    for (int i = threadIdx.x; i < ntile * 128; i += 256) Bs[i] = Bg[i];
  }

  int wave = threadIdx.x >> 6;
  int lane = threadIdx.x & 63;
  int v0   = blockIdx.x * 64 + wave * 16;
  int row  = lane & 15, kg = lane >> 4;

  // A fragments: basis[c][v0+row][k], k = ks*32 + kg*8 + j   (f32 -> bf16)
  const float* ab = basis + ((size_t)c * NV + (v0 + row)) * NK + kg * 8;
  float4 a0 = *(const float4*)(ab);
  float4 a1 = *(const float4*)(ab + 4);
  float4 a2 = *(const float4*)(ab + 32);
  float4 a3 = *(const float4*)(ab + 36);
  short8 A0, A1;
  A0[0]=f2bf(a0.x); A0[1]=f2bf(a0.y); A0[2]=f2bf(a0.z); A0[3]=f2bf(a0.w);
  A0[4]=f2bf(a1.x); A0[5]=f2bf(a1.y); A0[6]=f2bf(a1.z); A0[7]=f2bf(a1.w);
  A1[0]=f2bf(a2.x); A1[1]=f2bf(a2.y); A1[2]=f2bf(a2.z); A1[3]=f2bf(a2.w);
  A1[4]=f2bf(a3.x); A1[5]=f2bf(a3.y); A1[6]=f2bf(a3.z); A1[7]=f2bf(a3.w);

  // epilogue lane roles: q -> (record lr, component comp); rowg -> vertex group
  int q = lane & 15, rowg = lane >> 4;
  int lr = q / 3, comp = q - 3 * lr;
  bool qok = (q < 15);
  float bvx[4], bvy[4], bvz[4];
#pragma unroll
  for (int j = 0; j < 4; ++j) {
    const float* bp = basev + ((size_t)c * NV + (v0 + rowg * 4 + j)) * 3;
    bvx[j] = bp[0]; bvy[j] = bp[1]; bvz[j] = bp[2];
  }
  int sbase = lane & 48;
  int sx = sbase | (qok ? 3 * lr     : 0);
  int sy = sbase | (qok ? 3 * lr + 1 : 0);
  int sz = sbase | (qok ? 3 * lr + 2 : 0);

  // readout lane roles
  int rrec = lane / 12;            // 0..4 (lanes >= 60 idle)
  int roff = (lane % 12) * 4;      // float4 offset within the record's 48

  __syncthreads();   // s_B staged

  for (int t = ct0; t < ct1; ++t) {
    short8 B0, B1;
    if (t - ct0 < 8) {
      B0 = *(short8*)&s_B[(size_t)(t - ct0) * 1024 + lane * 8];
      B1 = *(short8*)&s_B[(size_t)(t - ct0) * 1024 + 512 + lane * 8];
    } else {
      const float4* BP4 = (const float4*)(Wf + 1280);
      float4 rb0 = BP4[(size_t)(t * 2 + 0) * 64 + lane];
      float4 rb1 = BP4[(size_t)(t * 2 + 1) * 64 + lane];
      B0 = *(short8*)&rb0; B1 = *(short8*)&rb1;
    }
    f32x4 acc = {0.0f, 0.0f, 0.0f, 0.0f};
    acc = __builtin_amdgcn_mfma_f32_16x16x32_bf16(A0, B0, acc, 0, 0, 0);
    acc = __builtin_amdgcn_mfma_f32_16x16x32_bf16(A1, B1, acc, 0, 0, 0);

    int nrec_ct = nrecs - (t - ct0) * 5;
    nrec_ct = (nrec_ct > 5) ? 5 : nrec_ct;
    bool valid = qok && (lr < nrec_ct);
    int rec = rec0 + (t - ct0) * 5 + (valid ? lr : 0);
    float4 P0 = *(const float4*)(Wf + 256 + rec * 8);
    float4 P1 = *(const float4*)(Wf + 256 + rec * 8 + 4);
    float scale = P0.x, qw = P0.y, qy = P0.z, tx = P0.w;
    float ty = P1.x, tz = P1.y, feff = P1.z;

#pragma unroll
    for (int j = 0; j < 4; ++j) {
      float dx_ = __shfl(acc[j], sx);
      float dy_ = __shfl(acc[j], sy);
      float dz_ = __shfl(acc[j], sz);

      float vx = (bvx[j] + dx_) * scale;
      float vy = (bvy[j] + dy_) * scale;
      float vz = (bvz[j] + dz_) * scale;
      float t2x = 2.0f * qy * vz;
      float t2z = -2.0f * qy * vx;
      float rx = vx + qw * t2x + qy * t2z;
      float ry = vy;
      float rz = vz + qw * t2z - qy * t2x;
      float wx = rx + tx, wy = ry + ty, wz = rz + tz;

      float zv = wz;
      float zsafe = (zv > -1e-4f) ? -1e-4f : zv;
      float inv = feff / (-zsafe);
      float px = (wx * inv * 0.5f + 0.5f) * (float)NR;
      float py = (wy * inv * 0.5f + 0.5f) * (float)NR;

      float ov = (comp == 0) ? px : ((comp == 1) ? py : -zv);
      if (qok) s_vp[wave][lr * 48 + (rowg * 4 + j) * 3 + comp] = ov;
    }
    // in-order per-wave DS: reads below see the writes above (no barrier)
    if (lane < 60 && rrec < nrec_ct) {
      float4 val = *(float4*)&s_vp[wave][rrec * 48 + roff];
      int rrec_g = rec0 + (t - ct0) * 5 + rrec;
      int bb = Wi[32 + rrec_g];
      *(float4*)&out[OFF_VP + ((size_t)bb * NV + v0) * 3 + roff] = val;
    }
  }
}

// ---- kernel 3: batch-major mask build, 1024 threads, float4-coalesced -------
__global__ __launch_bounds__(1024) void mask_kernel(float* __restrict__ out) {
  int b   = blockIdx.x;
  int tid = threadIdx.x;
  __shared__ float m[NR * NR];   // 64 KB
  float4 z4; z4.x = 0.0f; z4.y = 0.0f; z4.z = 0.0f; z4.w = 0.0f;
#pragma unroll
  for (int i = 0; i < 4; ++i) ((float4*)m)[tid + i * 1024] = z4;
  __syncthreads();
  const float4* vb4 = (const float4*)(out + OFF_VP + (size_t)b * NV * 3);
#pragma unroll
  for (int i = 0; i < 4; ++i) {
    int g = tid + i * 1024;              // vertex group of 4 (floats 12g..12g+11)
    float4 w0 = vb4[3 * g + 0];
    float4 w1 = vb4[3 * g + 1];
    float4 w2 = vb4[3 * g + 2];
    // pairs: (w0.x,w0.y) (w0.w,w1.x) (w1.z,w1.w) (w2.y,w2.z)
    float pxs0 = w0.x, pys0 = w0.y;
    float pxs1 = w0.w, pys1 = w1.x;
    float pxs2 = w1.z, pys2 = w1.w;
    float pxs3 = w2.y, pys3 = w2.z;
    int xi, yi;
    xi = (int)fminf(fmaxf(pxs0, 0.0f), 127.0f);
    yi = (int)fminf(fmaxf(pys0, 0.0f), 127.0f);
    m[yi * NR + xi] = 1.0f;
    xi = (int)fminf(fmaxf(pxs1, 0.0f), 127.0f);
    yi = (int)fminf(fmaxf(pys1, 0.0f), 127.0f);
    m[yi * NR + xi] = 1.0f;
    xi = (int)fminf(fmaxf(pxs2, 0.0f), 127.0f);
    yi = (int)fminf(fmaxf(pys2, 0.0f), 127.0f);
    m[yi * NR + xi] = 1.0f;
    xi = (int)fminf(fmaxf(pxs3, 0.0f), 127.0f);
    yi = (int)fminf(fmaxf(pys3, 0.0f), 127.0f);
    m[yi * NR + xi] = 1.0f;
  }
  __syncthreads();
  float4* mo = (float4*)(out + OFF_MASKS + ((size_t)b << 14));
#pragma unroll
  for (int i = 0; i < 4; ++i) mo[tid + i * 1024] = ((float4*)m)[tid + i * 1024];
}

extern "C" void kernel_launch(void* const* d_in, const int* in_sizes, int n_in,
                              void* d_out, int out_size, void* d_ws, size_t ws_size,
                              hipStream_t stream) {
  const float* roi    = (const float*)d_in[0];
  const float* focals = (const float*)d_in[1];
  const float* td     = (const float*)d_in[2];
  const float* t2     = (const float*)d_in[3];
  const float* ls     = (const float*)d_in[4];
  const float* ld     = (const float*)d_in[5];
  const float* cp     = (const float*)d_in[6];
  const float* fc     = (const float*)d_in[7];
  const float* bv     = (const float*)d_in[8];
  const float* fb     = (const float*)d_in[9];
  float* out = (float*)d_out;
  int*   Wi  = (int*)d_ws;
  float* Wf  = (float*)d_ws;

  prep_kernel<<<dim3(17), dim3(256), 0, stream>>>(
      roi, focals, td, t2, ls, ld, cp, fc, out, Wi, Wf);
  verts_kernel<<<dim3(256, 8), dim3(256), 0, stream>>>(
      bv, fb, Wi, Wf, out);
  mask_kernel<<<dim3(NB), dim3(1024), 0, stream>>>(out);
}